// Round 1
// baseline (10668.902 us; speedup 1.0000x reference)
//
#include <hip/hip_runtime.h>
#include <math.h>

#define SEQ    197
#define BATCH  32
#define ROWS   (BATCH * SEQ)      // 6304
#define DIM    512
#define NHEADS 8
#define DHEAD  64
#define NDEPTH 12
#define MLPD   2048
#define PD     432
#define GRIDP  14
#define NPATCH 196
#define EPSF   1e-5f

// ---------------------------------------------------------------------------
// Patch embedding: x[b, 1+p, :] = patch_vec(b,p) @ patch_w + patch_b + pos_emb
// plus cls row: x[b, 0, :] = cls + pos_emb[0]
// ---------------------------------------------------------------------------
__global__ __launch_bounds__(256) void patch_embed_kernel(
    const float* __restrict__ img, const float* __restrict__ pw,
    const float* __restrict__ pb, const float* __restrict__ cls,
    const float* __restrict__ pos, float* __restrict__ x)
{
    const int t = threadIdx.x;
    const int blk = blockIdx.x;
    if (blk >= BATCH * NPATCH) {
        // cls rows
        const int b = blk - BATCH * NPATCH;
        float* xr = x + (size_t)b * SEQ * DIM;
        xr[t]       = cls[t]       + pos[t];
        xr[t + 256] = cls[t + 256] + pos[t + 256];
        return;
    }
    const int b = blk / NPATCH;
    const int p = blk % NPATCH;
    const int gy = p / GRIDP, gx = p % GRIDP;

    __shared__ float pv[PD];
    for (int e = t; e < PD; e += 256) {
        const int c = e / 144;
        const int r = e % 144;
        const int fy = r / 12, fx = r % 12;
        const int py = gy * 8 - 2 + fy;
        const int px = gx * 8 - 2 + fx;
        float v = 0.f;
        if (py >= 0 && py < 112 && px >= 0 && px < 112)
            v = img[((size_t)(b * 3 + c) * 112 + py) * 112 + px];
        pv[e] = v;
    }
    __syncthreads();

    float acc0 = 0.f, acc1 = 0.f;
    #pragma unroll 4
    for (int k = 0; k < PD; ++k) {
        const float a = pv[k];
        const float* wr = pw + (size_t)k * DIM;
        acc0 = fmaf(a, wr[t], acc0);
        acc1 = fmaf(a, wr[t + 256], acc1);
    }
    const size_t row = (size_t)(b * SEQ + 1 + p) * DIM;
    const size_t prow = (size_t)(1 + p) * DIM;
    x[row + t]       = acc0 + pb[t]       + pos[prow + t];
    x[row + t + 256] = acc1 + pb[t + 256] + pos[prow + t + 256];
}

// ---------------------------------------------------------------------------
// Row LayerNorm over 512 elems. One block per row.
// ---------------------------------------------------------------------------
__global__ __launch_bounds__(256) void ln_kernel(
    const float* __restrict__ in, float* __restrict__ out,
    const float* __restrict__ g, const float* __restrict__ bta,
    size_t in_stride, size_t out_stride)
{
    const int r = blockIdx.x;
    const int t = threadIdx.x;
    const float* ip = in + (size_t)r * in_stride;
    const float v0 = ip[t];
    const float v1 = ip[t + 256];
    float s = v0 + v1;
    float ss = v0 * v0 + v1 * v1;
    #pragma unroll
    for (int off = 32; off > 0; off >>= 1) {
        s  += __shfl_xor(s, off);
        ss += __shfl_xor(ss, off);
    }
    __shared__ float rs[4], rss[4];
    if ((t & 63) == 0) { rs[t >> 6] = s; rss[t >> 6] = ss; }
    __syncthreads();
    s  = rs[0] + rs[1] + rs[2] + rs[3];
    ss = rss[0] + rss[1] + rss[2] + rss[3];
    const float mu  = s * (1.f / 512.f);
    const float var = ss * (1.f / 512.f) - mu * mu;
    const float inv = rsqrtf(var + EPSF);
    float* op = out + (size_t)r * out_stride;
    op[t]       = (v0 - mu) * inv * g[t]       + bta[t];
    op[t + 256] = (v1 - mu) * inv * g[t + 256] + bta[t + 256];
}

// ---------------------------------------------------------------------------
// Fused GEMM: C[M,N] = epilogue(A[M,K] @ W[K,N] + bias)
// mode 0: store; mode 1: C += v (residual accumulate); mode 2: exact GELU
// 64x64 tile, BK=16, 256 threads, 4x4 per thread.
// ---------------------------------------------------------------------------
__global__ __launch_bounds__(256) void gemm_kernel(
    const float* __restrict__ A, const float* __restrict__ W,
    const float* __restrict__ bias, float* __restrict__ C,
    int M, int N, int K, int mode)
{
    __shared__ float As[16][68];   // [k][m], padded: 68*4B=272B rows (16B-aligned)
    __shared__ float Bs[16][64];   // [k][n]
    const int t  = threadIdx.x;
    const int tx = t & 15;
    const int ty = t >> 4;
    const int bn = blockIdx.x * 64;
    const int bm = blockIdx.y * 64;

    const int am = t >> 2;          // 0..63 (m within tile)
    const int ac = (t & 3) * 4;     // 0,4,8,12 (k quad)
    const int wr = t >> 4;          // 0..15 (k row)
    const int wc = (t & 15) * 4;    // 0..60 (n quad)

    float acc[4][4] = {};

    for (int k0 = 0; k0 < K; k0 += 16) {
        const int m = bm + am;
        float4 av = make_float4(0.f, 0.f, 0.f, 0.f);
        if (m < M) av = *(const float4*)(A + (size_t)m * K + k0 + ac);
        As[ac + 0][am] = av.x;
        As[ac + 1][am] = av.y;
        As[ac + 2][am] = av.z;
        As[ac + 3][am] = av.w;
        const float4 wv = *(const float4*)(W + (size_t)(k0 + wr) * N + bn + wc);
        *(float4*)(&Bs[wr][wc]) = wv;
        __syncthreads();
        #pragma unroll
        for (int k = 0; k < 16; ++k) {
            const float4 a4 = *(const float4*)(&As[k][ty * 4]);
            const float4 b4 = *(const float4*)(&Bs[k][tx * 4]);
            const float a[4] = {a4.x, a4.y, a4.z, a4.w};
            const float bb[4] = {b4.x, b4.y, b4.z, b4.w};
            #pragma unroll
            for (int i = 0; i < 4; ++i)
                #pragma unroll
                for (int j = 0; j < 4; ++j)
                    acc[i][j] = fmaf(a[i], bb[j], acc[i][j]);
        }
        __syncthreads();
    }

    const int n = bn + tx * 4;
    float4 bv = make_float4(0.f, 0.f, 0.f, 0.f);
    if (bias) bv = *(const float4*)(bias + n);
    #pragma unroll
    for (int i = 0; i < 4; ++i) {
        const int m = bm + ty * 4 + i;
        if (m >= M) continue;
        float4 v;
        v.x = acc[i][0] + bv.x;
        v.y = acc[i][1] + bv.y;
        v.z = acc[i][2] + bv.z;
        v.w = acc[i][3] + bv.w;
        if (mode == 2) {
            v.x = 0.5f * v.x * (1.f + erff(v.x * 0.70710678118654752f));
            v.y = 0.5f * v.y * (1.f + erff(v.y * 0.70710678118654752f));
            v.z = 0.5f * v.z * (1.f + erff(v.z * 0.70710678118654752f));
            v.w = 0.5f * v.w * (1.f + erff(v.w * 0.70710678118654752f));
        }
        float* cp = C + (size_t)m * N + n;
        if (mode == 1) {
            const float4 old = *(const float4*)cp;
            v.x += old.x; v.y += old.y; v.z += old.z; v.w += old.w;
        }
        *(float4*)cp = v;
    }
}

// ---------------------------------------------------------------------------
// Attention scores + softmax. Block per (b, h, i-half). K tile in LDS.
// qkv layout: (b, s, 1536) with q at 0, k at 512, v at 1024. q/k col = h*64+d.
// scores layout: (b, i, h, j)
// ---------------------------------------------------------------------------
__global__ __launch_bounds__(256) void attn_scores_kernel(
    const float* __restrict__ qkv, float* __restrict__ scores)
{
    const int bh = blockIdx.x;       // 0..255
    const int half = blockIdx.y;     // 0..1
    const int b = bh >> 3, h = bh & 7;
    const int t = threadIdx.x;

    __shared__ float Ks[SEQ][65];    // padded: conflict-free per-lane rows
    __shared__ float qrow[64];
    __shared__ float red[8];

    const size_t base = (size_t)b * SEQ * 1536;
    for (int L = t; L < SEQ * 16; L += 256) {
        const int j = L >> 4;
        const int d4 = (L & 15) * 4;
        const float4 kv = *(const float4*)(qkv + base + (size_t)j * 1536 + 512 + h * 64 + d4);
        Ks[j][d4 + 0] = kv.x;
        Ks[j][d4 + 1] = kv.y;
        Ks[j][d4 + 2] = kv.z;
        Ks[j][d4 + 3] = kv.w;
    }
    __syncthreads();

    const int i0 = half ? 99 : 0;
    const int i1 = half ? SEQ : 99;
    for (int i = i0; i < i1; ++i) {
        if (t < 64) qrow[t] = qkv[base + (size_t)i * 1536 + h * 64 + t];
        __syncthreads();
        float s = -1e30f;
        if (t < SEQ) {
            float acc = 0.f;
            #pragma unroll
            for (int d = 0; d < 64; ++d) acc = fmaf(qrow[d], Ks[t][d], acc);
            s = acc * 0.125f;   // DH^-0.5
        }
        float mx = s;
        #pragma unroll
        for (int off = 32; off > 0; off >>= 1) mx = fmaxf(mx, __shfl_xor(mx, off));
        if ((t & 63) == 0) red[t >> 6] = mx;
        __syncthreads();
        mx = fmaxf(fmaxf(red[0], red[1]), fmaxf(red[2], red[3]));
        const float p = (t < SEQ) ? __expf(s - mx) : 0.f;
        float sm = p;
        #pragma unroll
        for (int off = 32; off > 0; off >>= 1) sm += __shfl_xor(sm, off);
        if ((t & 63) == 0) red[4 + (t >> 6)] = sm;
        __syncthreads();
        sm = red[4] + red[5] + red[6] + red[7];
        if (t < SEQ)
            scores[((size_t)(b * SEQ + i) * 8 + h) * SEQ + t] = p / sm;
        __syncthreads();
    }
}

// ---------------------------------------------------------------------------
// Re-attention (head mix) + LayerNorm over heads + attn @ v.
// Block per (b, group of 4 queries). o layout: (b, s, 512), col = h*64+d.
// ---------------------------------------------------------------------------
__global__ __launch_bounds__(256) void reattn_av_kernel(
    const float* __restrict__ qkv, const float* __restrict__ scores,
    const float* __restrict__ rw, const float* __restrict__ lw,
    const float* __restrict__ lb, float* __restrict__ o)
{
    const int t = threadIdx.x;
    const int b = blockIdx.x;
    const int ig = blockIdx.y;

    __shared__ float aln[SEQ * 8];
    __shared__ float rws[64];
    __shared__ float lws[8], lbs[8];

    if (t < 64) rws[t] = rw[t];
    if (t < 8) { lws[t] = lw[t]; lbs[t] = lb[t]; }
    __syncthreads();

    const int h0 = t >> 6;   // wave id: 0..3
    const size_t vbase = (size_t)b * SEQ * 1536 + 1024;

    for (int ii = 0; ii < 4; ++ii) {
        const int i = ig * 4 + ii;
        if (i >= SEQ) break;
        if (t < SEQ) {
            const float* sp = scores + (size_t)(b * SEQ + i) * 8 * SEQ + t;
            float a[8];
            #pragma unroll
            for (int h = 0; h < 8; ++h) a[h] = sp[(size_t)h * SEQ];
            float m[8];
            float mu = 0.f;
            #pragma unroll
            for (int g = 0; g < 8; ++g) {
                float s = 0.f;
                #pragma unroll
                for (int h = 0; h < 8; ++h) s = fmaf(a[h], rws[h * 8 + g], s);
                m[g] = s;
                mu += s;
            }
            mu *= 0.125f;
            float var = 0.f;
            #pragma unroll
            for (int g = 0; g < 8; ++g) { const float d = m[g] - mu; var = fmaf(d, d, var); }
            var *= 0.125f;
            const float inv = rsqrtf(var + EPSF);
            #pragma unroll
            for (int g = 0; g < 8; ++g)
                aln[t * 8 + g] = (m[g] - mu) * inv * lws[g] + lbs[g];
        }
        __syncthreads();
        float acc0 = 0.f, acc1 = 0.f;
        for (int j = 0; j < SEQ; ++j) {
            const float* vr = qkv + vbase + (size_t)j * 1536;
            acc0 = fmaf(aln[j * 8 + h0],     vr[t],       acc0);
            acc1 = fmaf(aln[j * 8 + 4 + h0], vr[t + 256], acc1);
        }
        float* op = o + (size_t)(b * SEQ + i) * 512;
        op[t]       = acc0;
        op[t + 256] = acc1;
        __syncthreads();
    }
}

// ---------------------------------------------------------------------------
extern "C" void kernel_launch(void* const* d_in, const int* in_sizes, int n_in,
                              void* d_out, int out_size, void* d_ws, size_t ws_size,
                              hipStream_t stream)
{
    (void)in_sizes; (void)n_in; (void)out_size; (void)ws_size;

    const float* img       = (const float*)d_in[0];
    const float* patch_w   = (const float*)d_in[1];
    const float* patch_b   = (const float*)d_in[2];
    const float* cls_token = (const float*)d_in[3];
    const float* pos_emb   = (const float*)d_in[4];
    const float* ln1_w     = (const float*)d_in[5];
    const float* ln1_b     = (const float*)d_in[6];
    const float* qkv_w     = (const float*)d_in[7];
    const float* reattn_w  = (const float*)d_in[8];
    const float* reattn_lw = (const float*)d_in[9];
    const float* reattn_lb = (const float*)d_in[10];
    const float* out_w     = (const float*)d_in[11];
    const float* out_b     = (const float*)d_in[12];
    const float* ln2_w     = (const float*)d_in[13];
    const float* ln2_b     = (const float*)d_in[14];
    const float* ff1_w     = (const float*)d_in[15];
    const float* ff1_b     = (const float*)d_in[16];
    const float* ff2_w     = (const float*)d_in[17];
    const float* ff2_b     = (const float*)d_in[18];
    const float* head_lw   = (const float*)d_in[19];
    const float* head_lb   = (const float*)d_in[20];
    float* out = (float*)d_out;

    float* ws = (float*)d_ws;
    float* x    = ws;                                // ROWS*512  = 3,227,648
    float* hbuf = x + (size_t)ROWS * DIM;            // ROWS*512
    float* qkv  = hbuf + (size_t)ROWS * DIM;         // ROWS*1536 = 9,682,944
    float* big  = qkv + (size_t)ROWS * 1536;         // max(scores 9.94M, mid 12.9M) floats
    float* scores = big;
    float* mid    = big;

    // patch embedding + cls + pos
    patch_embed_kernel<<<BATCH * NPATCH + BATCH, 256, 0, stream>>>(
        img, patch_w, patch_b, cls_token, pos_emb, x);

    for (int l = 0; l < NDEPTH; ++l) {
        // h_in = LN(x)
        ln_kernel<<<ROWS, 256, 0, stream>>>(x, hbuf, ln1_w + l * DIM, ln1_b + l * DIM, DIM, DIM);
        // qkv = h_in @ qkv_w (no bias)
        gemm_kernel<<<dim3(1536 / 64, (ROWS + 63) / 64), 256, 0, stream>>>(
            hbuf, qkv_w + (size_t)l * DIM * 1536, nullptr, qkv, ROWS, 1536, DIM, 0);
        // softmax(q k^T / 8)
        attn_scores_kernel<<<dim3(BATCH * NHEADS, 2), 256, 0, stream>>>(qkv, scores);
        // re-attention + head-LN + @v -> hbuf
        reattn_av_kernel<<<dim3(BATCH, (SEQ + 3) / 4), 256, 0, stream>>>(
            qkv, scores, reattn_w + l * 64, reattn_lw + l * 8, reattn_lb + l * 8, hbuf);
        // x += o @ out_w + out_b
        gemm_kernel<<<dim3(DIM / 64, (ROWS + 63) / 64), 256, 0, stream>>>(
            hbuf, out_w + (size_t)l * DIM * DIM, out_b + l * DIM, x, ROWS, DIM, DIM, 1);
        // h2 = LN(x)
        ln_kernel<<<ROWS, 256, 0, stream>>>(x, hbuf, ln2_w + l * DIM, ln2_b + l * DIM, DIM, DIM);
        // mid = gelu(h2 @ ff1_w + ff1_b)
        gemm_kernel<<<dim3(MLPD / 64, (ROWS + 63) / 64), 256, 0, stream>>>(
            hbuf, ff1_w + (size_t)l * DIM * MLPD, ff1_b + l * MLPD, mid, ROWS, MLPD, DIM, 2);
        // x += mid @ ff2_w + ff2_b
        gemm_kernel<<<dim3(DIM / 64, (ROWS + 63) / 64), 256, 0, stream>>>(
            mid, ff2_w + (size_t)l * MLPD * DIM, ff2_b + l * DIM, x, ROWS, DIM, MLPD, 1);
    }

    // head LN on token 0 of each batch row -> out
    ln_kernel<<<BATCH, 256, 0, stream>>>(x, out, head_lw, head_lb, (size_t)SEQ * DIM, DIM);
}

// Round 2
// 5369.086 us; speedup vs baseline: 1.9871x; 1.9871x over previous
//
#include <hip/hip_runtime.h>
#include <math.h>

#define SEQ    197
#define BATCH  32
#define ROWS   (BATCH * SEQ)      // 6304
#define MPAD   6400               // padded row count (50 x 128 tiles)
#define DIM    512
#define NHEADS 8
#define NDEPTH 12
#define MLPD   2048
#define PD     432
#define GRIDP  14
#define NPATCH 196
#define EPSF   1e-5f

typedef unsigned short ushort_t;
typedef __attribute__((ext_vector_type(8))) short  short8;
typedef __attribute__((ext_vector_type(4))) float  floatx4;

__device__ __forceinline__ float bf2f(ushort_t u) {
    union { unsigned int i; float f; } v; v.i = ((unsigned int)u) << 16; return v.f;
}
__device__ __forceinline__ ushort_t f2bf(float f) {
    union { float f; unsigned int i; } v; v.f = f;
    unsigned int r = v.i + 0x7fffu + ((v.i >> 16) & 1u);
    return (ushort_t)(r >> 16);
}
__device__ __forceinline__ void gl2lds16(const ushort_t* g, ushort_t* l) {
    __builtin_amdgcn_global_load_lds(
        (const __attribute__((address_space(1))) unsigned int*)g,
        (__attribute__((address_space(3))) unsigned int*)l, 16, 0, 0);
}

// ---------------------------------------------------------------------------
// Weight transpose + fp32->bf16: Wt[l][n][k] = bf16(W[l][k][n])
// grid (N/32, K/32, layers), 256 threads
// ---------------------------------------------------------------------------
__global__ __launch_bounds__(256) void wtrans_kernel(
    const float* __restrict__ W, ushort_t* __restrict__ Wt, int K, int N)
{
    const int l = blockIdx.z;
    W  += (size_t)l * K * N;
    Wt += (size_t)l * K * N;
    const int n0 = blockIdx.x * 32;
    const int k0 = blockIdx.y * 32;
    const int t = threadIdx.x;

    __shared__ float tile[32][33];
    {
        const int row = t >> 3;          // k within tile
        const int cq  = (t & 7) * 4;     // n quad
        const float4 v = *(const float4*)(W + (size_t)(k0 + row) * N + n0 + cq);
        tile[row][cq + 0] = v.x;
        tile[row][cq + 1] = v.y;
        tile[row][cq + 2] = v.z;
        tile[row][cq + 3] = v.w;
    }
    __syncthreads();
    {
        const int n  = t >> 3;           // n within tile
        const int kq = (t & 7) * 4;      // k quad
        ushort4 o;
        o.x = f2bf(tile[kq + 0][n]);
        o.y = f2bf(tile[kq + 1][n]);
        o.z = f2bf(tile[kq + 2][n]);
        o.w = f2bf(tile[kq + 3][n]);
        *(ushort4*)(Wt + (size_t)(n0 + n) * K + k0 + kq) = o;
    }
}

// ---------------------------------------------------------------------------
// Patch embedding (fp32): x[b,1+p,:] = patch @ patch_w + patch_b + pos; cls row
// ---------------------------------------------------------------------------
__global__ __launch_bounds__(256) void patch_embed_kernel(
    const float* __restrict__ img, const float* __restrict__ pw,
    const float* __restrict__ pb, const float* __restrict__ cls,
    const float* __restrict__ pos, float* __restrict__ x)
{
    const int t = threadIdx.x;
    const int blk = blockIdx.x;
    if (blk >= BATCH * NPATCH) {
        const int b = blk - BATCH * NPATCH;
        float* xr = x + (size_t)b * SEQ * DIM;
        xr[t]       = cls[t]       + pos[t];
        xr[t + 256] = cls[t + 256] + pos[t + 256];
        return;
    }
    const int b = blk / NPATCH;
    const int p = blk % NPATCH;
    const int gy = p / GRIDP, gx = p % GRIDP;

    __shared__ float pv[PD];
    for (int e = t; e < PD; e += 256) {
        const int c = e / 144;
        const int r = e % 144;
        const int fy = r / 12, fx = r % 12;
        const int py = gy * 8 - 2 + fy;
        const int px = gx * 8 - 2 + fx;
        float v = 0.f;
        if (py >= 0 && py < 112 && px >= 0 && px < 112)
            v = img[((size_t)(b * 3 + c) * 112 + py) * 112 + px];
        pv[e] = v;
    }
    __syncthreads();

    float acc0 = 0.f, acc1 = 0.f;
    #pragma unroll 4
    for (int k = 0; k < PD; ++k) {
        const float a = pv[k];
        const float* wr = pw + (size_t)k * DIM;
        acc0 = fmaf(a, wr[t], acc0);
        acc1 = fmaf(a, wr[t + 256], acc1);
    }
    const size_t row = (size_t)(b * SEQ + 1 + p) * DIM;
    const size_t prow = (size_t)(1 + p) * DIM;
    x[row + t]       = acc0 + pb[t]       + pos[prow + t];
    x[row + t + 256] = acc1 + pb[t + 256] + pos[prow + t + 256];
}

// ---------------------------------------------------------------------------
// Row LayerNorm over 512 elems, fp32 in, bf16 or fp32 out.
// ---------------------------------------------------------------------------
__global__ __launch_bounds__(256) void ln_kernel(
    const float* __restrict__ in, void* __restrict__ outp,
    const float* __restrict__ g, const float* __restrict__ bta,
    size_t in_stride, size_t out_stride, int out_bf16)
{
    const int r = blockIdx.x;
    const int t = threadIdx.x;
    const float* ip = in + (size_t)r * in_stride;
    const float v0 = ip[t];
    const float v1 = ip[t + 256];
    float s = v0 + v1;
    float ss = v0 * v0 + v1 * v1;
    #pragma unroll
    for (int off = 32; off > 0; off >>= 1) {
        s  += __shfl_xor(s, off);
        ss += __shfl_xor(ss, off);
    }
    __shared__ float rs[4], rss[4];
    if ((t & 63) == 0) { rs[t >> 6] = s; rss[t >> 6] = ss; }
    __syncthreads();
    s  = rs[0] + rs[1] + rs[2] + rs[3];
    ss = rss[0] + rss[1] + rss[2] + rss[3];
    const float mu  = s * (1.f / 512.f);
    const float var = ss * (1.f / 512.f) - mu * mu;
    const float inv = rsqrtf(var + EPSF);
    const float o0 = (v0 - mu) * inv * g[t]       + bta[t];
    const float o1 = (v1 - mu) * inv * g[t + 256] + bta[t + 256];
    if (out_bf16) {
        ushort_t* op = (ushort_t*)outp + (size_t)r * out_stride;
        op[t]       = f2bf(o0);
        op[t + 256] = f2bf(o1);
    } else {
        float* op = (float*)outp + (size_t)r * out_stride;
        op[t]       = o0;
        op[t + 256] = o1;
    }
}

// ---------------------------------------------------------------------------
// bf16 MFMA GEMM (m97 structure): C[M,N] = epi(A[M,K] @ Bt[N,K]^T + bias)
// 128x128 tile, BK=32, 256 threads (4 waves, 2x2 of 64x64), 4x4 frags/wave.
// mode 0: Cb = bf16(acc [+bias]);  mode 1: Cx += acc+bias (fp32 residual);
// mode 2: Cb = bf16(gelu(acc+bias))
// ---------------------------------------------------------------------------
__global__ __launch_bounds__(256) void gemm_bf16_kernel(
    const ushort_t* __restrict__ A, const ushort_t* __restrict__ Bt,
    const float* __restrict__ bias, ushort_t* __restrict__ Cb,
    float* __restrict__ Cx, int N, int K, int mode)
{
    __shared__ ushort_t As[128 * 32];
    __shared__ ushort_t Bs[128 * 32];
    const int t = threadIdx.x;
    const int l = t & 63;
    const int w = t >> 6;
    const int bm = blockIdx.y * 128;
    const int bn = blockIdx.x * 128;
    const int wm = (w & 1) * 64;
    const int wn = (w >> 1) * 64;

    const ushort_t* ga = A  + (size_t)(bm + w * 32 + (l >> 2)) * K + (l & 3) * 8;
    const ushort_t* gb = Bt + (size_t)(bn + w * 32 + (l >> 2)) * K + (l & 3) * 8;
    ushort_t* la = As + w * 1024;
    ushort_t* lb = Bs + w * 1024;
    const size_t rowK16 = (size_t)16 * K;

    floatx4 acc[4][4];
    #pragma unroll
    for (int i = 0; i < 4; ++i)
        #pragma unroll
        for (int j = 0; j < 4; ++j)
            acc[i][j] = (floatx4){0.f, 0.f, 0.f, 0.f};

    const int fr = l & 15;
    const int kq = (l >> 4) * 8;

    for (int k0 = 0; k0 < K; k0 += 32) {
        gl2lds16(ga + k0,          la);
        gl2lds16(ga + k0 + rowK16, la + 512);
        gl2lds16(gb + k0,          lb);
        gl2lds16(gb + k0 + rowK16, lb + 512);
        __syncthreads();
        short8 af[4], bfr[4];
        #pragma unroll
        for (int i = 0; i < 4; ++i)
            af[i] = *(const short8*)(As + (wm + i * 16 + fr) * 32 + kq);
        #pragma unroll
        for (int j = 0; j < 4; ++j)
            bfr[j] = *(const short8*)(Bs + (wn + j * 16 + fr) * 32 + kq);
        #pragma unroll
        for (int i = 0; i < 4; ++i)
            #pragma unroll
            for (int j = 0; j < 4; ++j)
                acc[i][j] = __builtin_amdgcn_mfma_f32_16x16x32_bf16(
                    af[i], bfr[j], acc[i][j], 0, 0, 0);
        __syncthreads();
    }

    float bv[4];
    #pragma unroll
    for (int j = 0; j < 4; ++j)
        bv[j] = bias ? bias[bn + wn + j * 16 + fr] : 0.f;

    const int r0 = (l >> 4) * 4;
    if (mode == 1) {
        #pragma unroll
        for (int i = 0; i < 4; ++i)
            #pragma unroll
            for (int r = 0; r < 4; ++r) {
                const size_t row = (size_t)(bm + wm + i * 16 + r0 + r);
                float* cp = Cx + row * N + bn + wn + fr;
                #pragma unroll
                for (int j = 0; j < 4; ++j)
                    cp[j * 16] += acc[i][j][r] + bv[j];
            }
    } else if (mode == 2) {
        #pragma unroll
        for (int i = 0; i < 4; ++i)
            #pragma unroll
            for (int r = 0; r < 4; ++r) {
                const size_t row = (size_t)(bm + wm + i * 16 + r0 + r);
                ushort_t* cp = Cb + row * N + bn + wn + fr;
                #pragma unroll
                for (int j = 0; j < 4; ++j) {
                    const float v = acc[i][j][r] + bv[j];
                    cp[j * 16] = f2bf(0.5f * v * (1.f + erff(v * 0.70710678118654752f)));
                }
            }
    } else {
        #pragma unroll
        for (int i = 0; i < 4; ++i)
            #pragma unroll
            for (int r = 0; r < 4; ++r) {
                const size_t row = (size_t)(bm + wm + i * 16 + r0 + r);
                ushort_t* cp = Cb + row * N + bn + wn + fr;
                #pragma unroll
                for (int j = 0; j < 4; ++j)
                    cp[j * 16] = f2bf(acc[i][j][r] + bv[j]);
            }
    }
}

// ---------------------------------------------------------------------------
// Attention scores + softmax. qkv bf16 (row,1536): q@0,k@512,v@1024.
// scores fp32 layout (b, i, h, j). Block per (b,h,i-half).
// ---------------------------------------------------------------------------
__global__ __launch_bounds__(256) void attn_scores_kernel(
    const ushort_t* __restrict__ qkv, float* __restrict__ scores)
{
    const int bh = blockIdx.x;
    const int half = blockIdx.y;
    const int b = bh >> 3, h = bh & 7;
    const int t = threadIdx.x;

    __shared__ float Ks[SEQ][65];
    __shared__ float qrow[64];
    __shared__ float red[8];

    const size_t base = (size_t)(b * SEQ) * 1536;
    for (int L = t; L < SEQ * 16; L += 256) {
        const int j = L >> 4;
        const int d4 = (L & 15) * 4;
        const ushort4 kv = *(const ushort4*)(qkv + base + (size_t)j * 1536 + 512 + h * 64 + d4);
        Ks[j][d4 + 0] = bf2f(kv.x);
        Ks[j][d4 + 1] = bf2f(kv.y);
        Ks[j][d4 + 2] = bf2f(kv.z);
        Ks[j][d4 + 3] = bf2f(kv.w);
    }
    __syncthreads();

    const int i0 = half ? 99 : 0;
    const int i1 = half ? SEQ : 99;
    for (int i = i0; i < i1; ++i) {
        if (t < 64) qrow[t] = bf2f(qkv[base + (size_t)i * 1536 + h * 64 + t]);
        __syncthreads();
        float s = -1e30f;
        if (t < SEQ) {
            float acc = 0.f;
            #pragma unroll
            for (int d = 0; d < 64; ++d) acc = fmaf(qrow[d], Ks[t][d], acc);
            s = acc * 0.125f;
        }
        float mx = s;
        #pragma unroll
        for (int off = 32; off > 0; off >>= 1) mx = fmaxf(mx, __shfl_xor(mx, off));
        if ((t & 63) == 0) red[t >> 6] = mx;
        __syncthreads();
        mx = fmaxf(fmaxf(red[0], red[1]), fmaxf(red[2], red[3]));
        const float p = (t < SEQ) ? __expf(s - mx) : 0.f;
        float sm = p;
        #pragma unroll
        for (int off = 32; off > 0; off >>= 1) sm += __shfl_xor(sm, off);
        if ((t & 63) == 0) red[4 + (t >> 6)] = sm;
        __syncthreads();
        sm = red[4] + red[5] + red[6] + red[7];
        if (t < SEQ)
            scores[((size_t)(b * SEQ + i) * 8 + h) * SEQ + t] = p / sm;
        __syncthreads();
    }
}

// ---------------------------------------------------------------------------
// Re-attention + LN-over-heads + attn@v. v bf16, output bf16 into hb.
// ---------------------------------------------------------------------------
__global__ __launch_bounds__(256) void reattn_av_kernel(
    const ushort_t* __restrict__ qkv, const float* __restrict__ scores,
    const float* __restrict__ rw, const float* __restrict__ lw,
    const float* __restrict__ lb, ushort_t* __restrict__ o)
{
    const int t = threadIdx.x;
    const int b = blockIdx.x;
    const int ig = blockIdx.y;

    __shared__ float aln[SEQ * 8];
    __shared__ float rws[64];
    __shared__ float lws[8], lbs[8];

    if (t < 64) rws[t] = rw[t];
    if (t < 8) { lws[t] = lw[t]; lbs[t] = lb[t]; }
    __syncthreads();

    const int h0 = t >> 6;
    const size_t vbase = (size_t)(b * SEQ) * 1536 + 1024;

    for (int ii = 0; ii < 4; ++ii) {
        const int i = ig * 4 + ii;
        if (i >= SEQ) break;
        if (t < SEQ) {
            const float* sp = scores + (size_t)(b * SEQ + i) * 8 * SEQ + t;
            float a[8];
            #pragma unroll
            for (int h = 0; h < 8; ++h) a[h] = sp[(size_t)h * SEQ];
            float m[8];
            float mu = 0.f;
            #pragma unroll
            for (int g = 0; g < 8; ++g) {
                float s = 0.f;
                #pragma unroll
                for (int h = 0; h < 8; ++h) s = fmaf(a[h], rws[h * 8 + g], s);
                m[g] = s;
                mu += s;
            }
            mu *= 0.125f;
            float var = 0.f;
            #pragma unroll
            for (int g = 0; g < 8; ++g) { const float d = m[g] - mu; var = fmaf(d, d, var); }
            var *= 0.125f;
            const float inv = rsqrtf(var + EPSF);
            #pragma unroll
            for (int g = 0; g < 8; ++g)
                aln[t * 8 + g] = (m[g] - mu) * inv * lws[g] + lbs[g];
        }
        __syncthreads();
        float acc0 = 0.f, acc1 = 0.f;
        for (int j = 0; j < SEQ; ++j) {
            const ushort_t* vr = qkv + vbase + (size_t)j * 1536;
            acc0 = fmaf(aln[j * 8 + h0],     bf2f(vr[t]),       acc0);
            acc1 = fmaf(aln[j * 8 + 4 + h0], bf2f(vr[t + 256]), acc1);
        }
        ushort_t* op = o + (size_t)(b * SEQ + i) * 512;
        op[t]       = f2bf(acc0);
        op[t + 256] = f2bf(acc1);
        __syncthreads();
    }
}

// ---------------------------------------------------------------------------
extern "C" void kernel_launch(void* const* d_in, const int* in_sizes, int n_in,
                              void* d_out, int out_size, void* d_ws, size_t ws_size,
                              hipStream_t stream)
{
    (void)in_sizes; (void)n_in; (void)out_size; (void)ws_size;

    const float* img       = (const float*)d_in[0];
    const float* patch_w   = (const float*)d_in[1];
    const float* patch_b   = (const float*)d_in[2];
    const float* cls_token = (const float*)d_in[3];
    const float* pos_emb   = (const float*)d_in[4];
    const float* ln1_w     = (const float*)d_in[5];
    const float* ln1_b     = (const float*)d_in[6];
    const float* qkv_w     = (const float*)d_in[7];
    const float* reattn_w  = (const float*)d_in[8];
    const float* reattn_lw = (const float*)d_in[9];
    const float* reattn_lb = (const float*)d_in[10];
    const float* out_w     = (const float*)d_in[11];
    const float* out_b     = (const float*)d_in[12];
    const float* ln2_w     = (const float*)d_in[13];
    const float* ln2_b     = (const float*)d_in[14];
    const float* ff1_w     = (const float*)d_in[15];
    const float* ff1_b     = (const float*)d_in[16];
    const float* ff2_w     = (const float*)d_in[17];
    const float* ff2_b     = (const float*)d_in[18];
    const float* head_lw   = (const float*)d_in[19];
    const float* head_lb   = (const float*)d_in[20];
    float* out = (float*)d_out;

    // workspace layout (bytes)
    char* p = (char*)d_ws;
    float* x = (float*)p;            p += (size_t)MPAD * DIM * 4;        // 13.1 MB
    ushort_t* hb = (ushort_t*)p;     p += (size_t)MPAD * DIM * 2;        // 6.6 MB
    ushort_t* qkvb = (ushort_t*)p;   p += (size_t)MPAD * 1536 * 2;       // 19.7 MB
    char* big = p;                   p += (size_t)41943040;              // 40 MB shared
    float* scores = (float*)big;                                        // 39.74 MB live: attn
    ushort_t* midb = (ushort_t*)big;                                    // 26.2 MB live: mlp
    ushort_t* qkv_wt = (ushort_t*)p; p += (size_t)NDEPTH * 1536 * 512 * 2;
    ushort_t* out_wt = (ushort_t*)p; p += (size_t)NDEPTH * 512 * 512 * 2;
    ushort_t* ff1_wt = (ushort_t*)p; p += (size_t)NDEPTH * 2048 * 512 * 2;
    ushort_t* ff2_wt = (ushort_t*)p; p += (size_t)NDEPTH * 512 * 2048 * 2;

    // one-time per-launch weight transpose + bf16 convert
    wtrans_kernel<<<dim3(1536 / 32, 512 / 32, NDEPTH), 256, 0, stream>>>(qkv_w, qkv_wt, 512, 1536);
    wtrans_kernel<<<dim3(512 / 32, 512 / 32, NDEPTH), 256, 0, stream>>>(out_w, out_wt, 512, 512);
    wtrans_kernel<<<dim3(2048 / 32, 512 / 32, NDEPTH), 256, 0, stream>>>(ff1_w, ff1_wt, 512, 2048);
    wtrans_kernel<<<dim3(512 / 32, 2048 / 32, NDEPTH), 256, 0, stream>>>(ff2_w, ff2_wt, 2048, 512);

    patch_embed_kernel<<<BATCH * NPATCH + BATCH, 256, 0, stream>>>(
        img, patch_w, patch_b, cls_token, pos_emb, x);

    for (int l = 0; l < NDEPTH; ++l) {
        ln_kernel<<<ROWS, 256, 0, stream>>>(x, hb, ln1_w + l * DIM, ln1_b + l * DIM, DIM, DIM, 1);
        gemm_bf16_kernel<<<dim3(1536 / 128, MPAD / 128), 256, 0, stream>>>(
            hb, qkv_wt + (size_t)l * 1536 * 512, nullptr, qkvb, nullptr, 1536, 512, 0);
        attn_scores_kernel<<<dim3(BATCH * NHEADS, 2), 256, 0, stream>>>(qkvb, scores);
        reattn_av_kernel<<<dim3(BATCH, (SEQ + 3) / 4), 256, 0, stream>>>(
            qkvb, scores, reattn_w + l * 64, reattn_lw + l * 8, reattn_lb + l * 8, hb);
        gemm_bf16_kernel<<<dim3(512 / 128, MPAD / 128), 256, 0, stream>>>(
            hb, out_wt + (size_t)l * 512 * 512, out_b + l * DIM, nullptr, x, 512, 512, 1);
        ln_kernel<<<ROWS, 256, 0, stream>>>(x, hb, ln2_w + l * DIM, ln2_b + l * DIM, DIM, DIM, 1);
        gemm_bf16_kernel<<<dim3(2048 / 128, MPAD / 128), 256, 0, stream>>>(
            hb, ff1_wt + (size_t)l * 2048 * 512, ff1_b + l * MLPD, midb, nullptr, 2048, 512, 2);
        gemm_bf16_kernel<<<dim3(512 / 128, MPAD / 128), 256, 0, stream>>>(
            midb, ff2_wt + (size_t)l * 512 * 2048, ff2_b + l * DIM, nullptr, x, 512, 2048, 1);
    }

    ln_kernel<<<BATCH, 256, 0, stream>>>(x, out, head_lw, head_lb, (size_t)SEQ * DIM, DIM, 0);
}